// Round 12
// baseline (221.227 us; speedup 1.0000x reference)
//
#include <hip/hip_runtime.h>
#include <hip/hip_bf16.h>

#define DM 1024
#define NH 16
#define HD 64
#define B_ 2
#define S_ 2048
#define M_ (B_*S_)   // 4096

typedef __attribute__((ext_vector_type(8))) short bf16x8;
typedef __attribute__((ext_vector_type(4))) float f32x4;
typedef __attribute__((ext_vector_type(16))) float f32x16;

__device__ __forceinline__ float bf2f(ushort u) {
  union { unsigned u32; float f; } c; c.u32 = ((unsigned)u) << 16; return c.f;
}
__device__ __forceinline__ ushort f2bf(float f) {
  union { float f; unsigned u32; } c; c.f = f;
  unsigned u = c.u32;
  unsigned r = (u + 0x7fffu + ((u >> 16) & 1u)) >> 16;
  return (ushort)r;
}
__device__ __forceinline__ unsigned fbits(float f) {
  union { float f; unsigned u; } c; c.f = f; return c.u;
}

// async global->LDS, 16 B per lane; LDS dest = wave-uniform base + lane*16
__device__ __forceinline__ void async16(const ushort* g, ushort* l) {
  __builtin_amdgcn_global_load_lds((const __attribute__((address_space(1))) void*)g,
                                   (__attribute__((address_space(3))) void*)l, 16, 0, 0);
}

// ---- fused prep: z<4 -> fp32 W[k][n] -> bf16 Wt[n][k]; z==4 -> fp32 x -> bf16 ----
__global__ void cvt_prep(const float* __restrict__ x, const float* __restrict__ W0,
                         const float* __restrict__ W1, const float* __restrict__ W2,
                         const float* __restrict__ W3, ushort* __restrict__ wt,
                         ushort* __restrict__ xb) {
  __shared__ float tile[64][65];
  int z = blockIdx.z;
  int tx = threadIdx.x, ty = threadIdx.y;   // block (64,4)
  if (z == 4) {
    int tid = ty * 64 + tx;
    size_t base4 = ((size_t)blockIdx.y * 16 + blockIdx.x) * 4096;  // float4 units
    const float4* xv = (const float4*)x;
    ushort4* ov = (ushort4*)xb;
    #pragma unroll
    for (int k = 0; k < 16; ++k) {
      float4 v = xv[base4 + k * 256 + tid];
      ushort4 o;
      o.x = f2bf(v.x); o.y = f2bf(v.y); o.z = f2bf(v.z); o.w = f2bf(v.w);
      ov[base4 + k * 256 + tid] = o;
    }
    return;
  }
  const float* W = (z == 0) ? W0 : (z == 1) ? W1 : (z == 2) ? W2 : W3;
  ushort* Wt = wt + (size_t)z * (DM * DM);
  int c0 = blockIdx.x * 64, r0 = blockIdx.y * 64;
  #pragma unroll
  for (int i = ty; i < 64; i += 4) tile[i][tx] = W[(size_t)(r0 + i) * DM + c0 + tx];
  __syncthreads();
  #pragma unroll
  for (int i = ty; i < 64; i += 4) Wt[(size_t)(c0 + i) * DM + r0 + tx] = f2bf(tile[tx][i]);
}

// ---------------- MFMA GEMM (unchanged from round 11) ----------------
template <int MODE, int BN>
__device__ __forceinline__ void gemm_body(const ushort* __restrict__ A,
                                          const ushort* __restrict__ Bt,
                                          ushort* __restrict__ Cb,
                                          float* __restrict__ Cf,
                                          ushort* As, ushort* Bs, ushort* Ts) {
  const int K = DM;
  constexpr int CN = BN / 32;                   // n-frags per wave
  int m0 = blockIdx.y * 128;
  int n0 = blockIdx.x * BN;
  int t = threadIdx.x;
  int lane = t & 63, wave = t >> 6;
  int wm = (wave >> 1) * 64, wn = (wave & 1) * (BN / 2);
  int lrow = lane & 15, quad = lane >> 4;

  int Ra = wave * 32;                           // A rows staged by this wave
  int Rb = wave * (BN / 4);                     // B rows staged by this wave
  int srow = lane >> 2, scol = (lane & 3) * 8;  // per-lane 16B chunk within 16-row group

  f32x4 acc[4][CN];
  #pragma unroll
  for (int r = 0; r < 4; ++r)
    #pragma unroll
    for (int c = 0; c < CN; ++c) acc[r][c] = (f32x4){0.f, 0.f, 0.f, 0.f};

  for (int k0 = 0; k0 < K; k0 += 32) {
    const ushort* ga = A + (size_t)(m0 + Ra + srow) * K + k0 + scol;
    const ushort* gb = Bt + (size_t)(n0 + Rb + srow) * K + k0 + scol;
    async16(ga,          As + Ra * 32);
    async16(ga + 16 * K, As + (Ra + 16) * 32);
    async16(gb,          Bs + Rb * 32);
    if (BN == 128) async16(gb + 16 * K, Bs + (Rb + 16) * 32);
    __syncthreads();

    bf16x8 af[4], bfr[CN];
    #pragma unroll
    for (int r = 0; r < 4; ++r)
      af[r] = *(const bf16x8*)(As + (wm + r * 16 + lrow) * 32 + quad * 8);
    #pragma unroll
    for (int c = 0; c < CN; ++c)
      bfr[c] = *(const bf16x8*)(Bs + (wn + c * 16 + lrow) * 32 + quad * 8);
    #pragma unroll
    for (int r = 0; r < 4; ++r)
      #pragma unroll
      for (int c = 0; c < CN; ++c)
        acc[r][c] = __builtin_amdgcn_mfma_f32_16x16x32_bf16(af[r], bfr[c], acc[r][c], 0, 0, 0);
    __syncthreads();
  }

  if constexpr (MODE == 2) {
    int bb = m0 >> 11;
    int s0base = m0 & 2047;
    #pragma unroll
    for (int H = 0; H < 2; ++H) {
      __syncthreads();
      if ((wave >> 1) == H) {
        #pragma unroll
        for (int r = 0; r < 4; ++r)
          #pragma unroll
          for (int c = 0; c < 4; ++c) {
            uint2 pk;
            pk.x = (unsigned)f2bf(acc[r][c][0]) | ((unsigned)f2bf(acc[r][c][1]) << 16);
            pk.y = (unsigned)f2bf(acc[r][c][2]) | ((unsigned)f2bf(acc[r][c][3]) << 16);
            *(uint2*)(Ts + (wn + c * 16 + lrow) * 72 + r * 16 + quad * 4) = pk;
          }
      }
      __syncthreads();
      #pragma unroll
      for (int i = 0; i < 4; ++i) {
        int id = t + i * 256;
        int nn = id >> 3, col = (id & 7) * 8;
        uint4 v = *(const uint4*)(Ts + nn * 72 + col);
        int h2 = (n0 >> 6) + (nn >> 6), d2 = nn & 63;
        size_t dst = (((size_t)(bb * NH + h2)) * HD + d2) * (size_t)S_ + s0base + H * 64 + col;
        *(uint4*)(Cb + dst) = v;
      }
    }
  } else {
    #pragma unroll
    for (int r = 0; r < 4; ++r) {
      #pragma unroll
      for (int c = 0; c < CN; ++c) {
        #pragma unroll
        for (int e = 0; e < 4; ++e) {
          int m = m0 + wm + r * 16 + quad * 4 + e;
          int n = n0 + wn + c * 16 + lrow;
          if (MODE == 0) {
            Cf[(size_t)m * DM + n] = acc[r][c][e];
          } else {
            int b = m >> 11, s = m & 2047, h = n >> 6, d = n & 63;
            Cb[(((size_t)(b * NH + h)) * S_ + s) * HD + d] = f2bf(acc[r][c][e]);
          }
        }
      }
    }
  }
}

__global__ __launch_bounds__(256, 2) void gemm_qkv(const ushort* __restrict__ A,
                                                   const ushort* __restrict__ wt,
                                                   ushort* __restrict__ qkv) {
  __shared__ __align__(16) ushort smem[9216];   // As[0:4096) Bs[4096:8192); Ts aliases [0:9216)
  ushort* As = smem;
  ushort* Bs = smem + 4096;
  ushort* Ts = smem;
  int z = blockIdx.z;
  if (z < 2)
    gemm_body<1, 128>(A, wt + (size_t)z * (DM * DM), qkv + (size_t)z * ((size_t)M_ * DM),
                      nullptr, As, Bs, Ts);
  else
    gemm_body<2, 128>(A, wt + (size_t)2 * (DM * DM), qkv + (size_t)2 * ((size_t)M_ * DM),
                      nullptr, As, Bs, Ts);
}

__global__ __launch_bounds__(256, 2) void gemm_out(const ushort* __restrict__ A,
                                                   const ushort* __restrict__ wt,
                                                   float* __restrict__ C) {
  __shared__ __align__(16) ushort As[128 * 32];
  __shared__ __align__(16) ushort Bs[64 * 32];
  gemm_body<0, 64>(A, wt, nullptr, C, As, Bs, nullptr);
}

// ---------------- MFMA flash attention v7: 32x32x16 + swizzled LDS ----------------
// Block = 128 thr = 2 waves; wave owns 32 hi-rows + 32 lo-rows of pair (p, 31-p).
// S^T = K*Q^T (A=K, B=Q; C col = q = lane&31, row = key via reg pattern).
// LDS stride 64 with chunk XOR-swizzle (chunk' = chunk ^ (row&7)) -> conflict-free.
// No-max softmax; diagonal-tile-only masking; double-buffered K/V staging.
#define EXPC 0.18033688011f   // 0.125 * log2(e)

struct AttnState {
  f32x16 o[2];   // [d-block 0/1], C-layout: col d = lane&31, row q via reg
  float l;       // partial sum for q = lane&31 over this lane's keys
};

template <bool MASKED>
__device__ __forceinline__ void attn_tile_compute32(
    int q0, int kt, const bf16x8 qf[4],
    const ushort* Kc, const ushort* Vc, ushort* pl,
    AttnState& st, int m31, int hi) {
  // ---- S^T = K·Q^T: 2 key-blocks x 4 d-frags ----
  f32x16 s[2];
  #pragma unroll
  for (int c = 0; c < 2; ++c) {
    f32x16 z = {0.f};
    #pragma unroll
    for (int f = 0; f < 4; ++f) {
      int row = c * 32 + m31;
      bf16x8 kf = *(const bf16x8*)(Kc + row * 64 + (((2 * f + hi) ^ (row & 7)) * 8));
      z = __builtin_amdgcn_mfma_f32_32x32x16_bf16(kf, qf[f], z, 0, 0, 0);
    }
    s[c] = z;
  }
  // ---- exp, mask(diag only), pack 4-key runs, swizzled b64 P writes ----
  int q = q0 + m31;
  #pragma unroll
  for (int c = 0; c < 2; ++c) {
    #pragma unroll
    for (int g = 0; g < 4; ++g) {
      int kbase = kt + c * 32 + g * 8 + hi * 4;    // key of e=0
      float pv[4];
      #pragma unroll
      for (int e = 0; e < 4; ++e) {
        float v = __builtin_amdgcn_exp2f(s[c][g * 4 + e] * EXPC);
        if (MASKED) v = (kbase + e <= q) ? v : 0.f;
        pv[e] = v;
        st.l += v;
      }
      uint2 pk;
      pk.x = __builtin_amdgcn_perm(fbits(pv[1]), fbits(pv[0]), 0x07060302u);
      pk.y = __builtin_amdgcn_perm(fbits(pv[3]), fbits(pv[2]), 0x07060302u);
      *(uint2*)(pl + m31 * 64 + (((g + 4 * c) ^ (m31 & 7)) * 8) + hi * 4) = pk;
    }
  }
  // ---- P A-frags (row q = m31, keys (lane>>5)*8+j+16f), swizzled b128 ----
  bf16x8 pf[4];
  #pragma unroll
  for (int f = 0; f < 4; ++f)
    pf[f] = *(const bf16x8*)(pl + m31 * 64 + (((2 * f + hi) ^ (m31 & 7)) * 8));
  // ---- PV: o[db] += P·V, B = Vt rows (d = db*32 + m31) ----
  #pragma unroll
  for (int db = 0; db < 2; ++db) {
    f32x16 z = st.o[db];
    #pragma unroll
    for (int f = 0; f < 4; ++f) {
      int rv = db * 32 + m31;
      bf16x8 vf = *(const bf16x8*)(Vc + rv * 64 + (((2 * f + hi) ^ (rv & 7)) * 8));
      z = __builtin_amdgcn_mfma_f32_32x32x16_bf16(pf[f], vf, z, 0, 0, 0);
    }
    st.o[db] = z;
  }
}

__global__ __launch_bounds__(128, 1) void attn_mfma(const ushort* __restrict__ Q,
                                                    const ushort* __restrict__ Kmat,
                                                    const ushort* __restrict__ Vt,
                                                    ushort* __restrict__ ctx) {
  __shared__ __align__(16) ushort Ks[2][64 * 64];    // [key][d], swizzled, 8 KB
  __shared__ __align__(16) ushort Vs[2][64 * 64];    // [d][key], swizzled
  __shared__ __align__(16) ushort plds[4][32 * 64];  // [wave*2 + stream], swizzled
  int t = threadIdx.x;             // 0..127
  int lane = t & 63, wave = t >> 6;
  int m31 = lane & 31, hi = lane >> 5;
  int bh = blockIdx.y;             // b*NH + h
  int p = blockIdx.x;              // pair index 0..15
  int qt_lo = p, qt_hi = 31 - p;
  const ushort* Kb = Kmat + (size_t)bh * S_ * HD;
  const ushort* Vb = Vt + (size_t)bh * HD * S_;
  ushort* pl_hi = plds[wave * 2];
  ushort* pl_lo = plds[wave * 2 + 1];
  int b = bh >> 4, h = bh & 15;

  // staging: 1024 16B-chunks (K 512 + V 512) over 128 threads = 8 per thread
  int c8t = t & 7;                 // chunk col (constant per thread)
  int rbase = t >> 3;              // chunk rows rbase + 16*i

  int q0_lo = qt_lo * 64 + wave * 32;
  int q0_hi = qt_hi * 64 + wave * 32;
  bf16x8 qlo[4], qhi[4];
  #pragma unroll
  for (int f = 0; f < 4; ++f) {
    qlo[f] = *(const bf16x8*)(Q + ((size_t)bh * S_ + q0_lo + m31) * HD + f * 16 + hi * 8);
    qhi[f] = *(const bf16x8*)(Q + ((size_t)bh * S_ + q0_hi + m31) * HD + f * 16 + hi * 8);
  }

  AttnState lo, hi_s;
  #pragma unroll
  for (int i = 0; i < 2; ++i) { lo.o[i] = (f32x16){0.f}; hi_s.o[i] = (f32x16){0.f}; }
  lo.l = 0.f; hi_s.l = 0.f;

  int kend = qt_hi * 64;
  int lo_end = qt_lo * 64;

  // prologue: stage tile 0 into buffer 0 (swizzled)
  #pragma unroll
  for (int i = 0; i < 4; ++i) {
    int r = rbase + 16 * i;
    int so = r * 64 + ((c8t ^ (r & 7)) * 8);
    *(uint4*)(Ks[0] + so) = *(const uint4*)(Kb + (size_t)r * HD + c8t * 8);
    *(uint4*)(Vs[0] + so) = *(const uint4*)(Vb + (size_t)r * S_ + c8t * 8);
  }
  __syncthreads();

  for (int kt = 0; kt <= kend; kt += 64) {
    int cur = (kt >> 6) & 1, nxt = cur ^ 1;
    bool has_next = (kt < kend);

    uint4 kr[4], vr[4];
    if (has_next) {
      int ktn = kt + 64;
      #pragma unroll
      for (int i = 0; i < 4; ++i) {
        int r = rbase + 16 * i;
        kr[i] = *(const uint4*)(Kb + (size_t)(ktn + r) * HD + c8t * 8);
        vr[i] = *(const uint4*)(Vb + (size_t)r * S_ + ktn + c8t * 8);
      }
    }

    if (kt < kend)
      attn_tile_compute32<false>(q0_hi, kt, qhi, Ks[cur], Vs[cur], pl_hi, hi_s, m31, hi);
    else
      attn_tile_compute32<true>(q0_hi, kt, qhi, Ks[cur], Vs[cur], pl_hi, hi_s, m31, hi);
    if (kt < lo_end)
      attn_tile_compute32<false>(q0_lo, kt, qlo, Ks[cur], Vs[cur], pl_lo, lo, m31, hi);
    else if (kt == lo_end)
      attn_tile_compute32<true>(q0_lo, kt, qlo, Ks[cur], Vs[cur], pl_lo, lo, m31, hi);

    if (has_next) {
      #pragma unroll
      for (int i = 0; i < 4; ++i) {
        int r = rbase + 16 * i;
        int so = r * 64 + ((c8t ^ (r & 7)) * 8);
        *(uint4*)(Ks[nxt] + so) = kr[i];
        *(uint4*)(Vs[nxt] + so) = vr[i];
      }
    }
    __syncthreads();
  }

  // ---- epilogue: combine l across lane-halves, normalize, store ----
  #pragma unroll
  for (int half = 0; half < 2; ++half) {
    AttnState& st = half ? hi_s : lo;
    int q0 = half ? q0_hi : q0_lo;
    float l = st.l + __shfl_xor(st.l, 32);
    float rl = 1.0f / l;               // valid per q = m31 (both halves)
    #pragma unroll
    for (int g = 0; g < 4; ++g) {
      #pragma unroll
      for (int e = 0; e < 4; ++e) {
        int qlocal = e + g * 8 + hi * 4;
        float rinv = __shfl(rl, qlocal);
        size_t base = ((size_t)b * S_ + q0 + qlocal) * DM + h * HD + m31;
        ctx[base]      = f2bf(st.o[0][g * 4 + e] * rinv);
        ctx[base + 32] = f2bf(st.o[1][g * 4 + e] * rinv);
      }
    }
  }
}

// ---------------- launch ----------------
extern "C" void kernel_launch(void* const* d_in, const int* in_sizes, int n_in,
                              void* d_out, int out_size, void* d_ws, size_t ws_size,
                              hipStream_t stream) {
  const float* x  = (const float*)d_in[0];
  const float* Wq = (const float*)d_in[1];
  const float* Wk = (const float*)d_in[2];
  const float* Wv = (const float*)d_in[3];
  const float* Wo = (const float*)d_in[4];
  float* out = (float*)d_out;
  ushort* ws = (ushort*)d_ws;

  ushort* xb  = ws;                                   // 4M elem bf16 x
  ushort* wt  = xb + (size_t)M_ * DM;                 // 4 x 1M elem (Wq^T,Wk^T,Wv^T,Wo^T) bf16
  ushort* qkv = wt + (size_t)4 * DM * DM;             // Q,K [b,h,s,d]; V^T [b,h,d,s] bf16
  ushort* ctx = qkv + (size_t)3 * M_ * DM;            // 4M elem [B,S,DM] bf16

  cvt_prep<<<dim3(16, 16, 5), dim3(64, 4), 0, stream>>>(x, Wq, Wk, Wv, Wo, wt, xb);
  gemm_qkv<<<dim3(DM / 128, M_ / 128, 3), 256, 0, stream>>>(xb, wt, qkv);
  attn_mfma<<<dim3(16, B_ * NH), 128, 0, stream>>>(qkv, qkv + (size_t)M_ * DM,
                                                   qkv + (size_t)2 * M_ * DM, ctx);
  gemm_out<<<dim3(DM / 64, M_ / 128), 256, 0, stream>>>(ctx, wt + (size_t)3 * DM * DM, out);
}

// Round 13
// 181.553 us; speedup vs baseline: 1.2185x; 1.2185x over previous
//
#include <hip/hip_runtime.h>
#include <hip/hip_bf16.h>

#define DM 1024
#define NH 16
#define HD 64
#define B_ 2
#define S_ 2048
#define M_ (B_*S_)   // 4096

typedef __attribute__((ext_vector_type(8))) short bf16x8;
typedef __attribute__((ext_vector_type(4))) float f32x4;

__device__ __forceinline__ float bf2f(ushort u) {
  union { unsigned u32; float f; } c; c.u32 = ((unsigned)u) << 16; return c.f;
}
__device__ __forceinline__ ushort f2bf(float f) {
  union { float f; unsigned u32; } c; c.f = f;
  unsigned u = c.u32;
  unsigned r = (u + 0x7fffu + ((u >> 16) & 1u)) >> 16;
  return (ushort)r;
}
__device__ __forceinline__ unsigned fbits(float f) {
  union { float f; unsigned u; } c; c.f = f; return c.u;
}

// async global->LDS, 16 B per lane; LDS dest = wave-uniform base + lane*16
__device__ __forceinline__ void async16(const ushort* g, ushort* l) {
  __builtin_amdgcn_global_load_lds((const __attribute__((address_space(1))) void*)g,
                                   (__attribute__((address_space(3))) void*)l, 16, 0, 0);
}

// ---- fused prep: z<4 -> fp32 W[k][n] -> bf16 Wt[n][k]; z==4 -> fp32 x -> bf16 ----
__global__ void cvt_prep(const float* __restrict__ x, const float* __restrict__ W0,
                         const float* __restrict__ W1, const float* __restrict__ W2,
                         const float* __restrict__ W3, ushort* __restrict__ wt,
                         ushort* __restrict__ xb) {
  __shared__ float tile[64][65];
  int z = blockIdx.z;
  int tx = threadIdx.x, ty = threadIdx.y;   // block (64,4)
  if (z == 4) {
    int tid = ty * 64 + tx;
    size_t base4 = ((size_t)blockIdx.y * 16 + blockIdx.x) * 4096;  // float4 units
    const float4* xv = (const float4*)x;
    ushort4* ov = (ushort4*)xb;
    #pragma unroll
    for (int k = 0; k < 16; ++k) {
      float4 v = xv[base4 + k * 256 + tid];
      ushort4 o;
      o.x = f2bf(v.x); o.y = f2bf(v.y); o.z = f2bf(v.z); o.w = f2bf(v.w);
      ov[base4 + k * 256 + tid] = o;
    }
    return;
  }
  const float* W = (z == 0) ? W0 : (z == 1) ? W1 : (z == 2) ? W2 : W3;
  ushort* Wt = wt + (size_t)z * (DM * DM);
  int c0 = blockIdx.x * 64, r0 = blockIdx.y * 64;
  #pragma unroll
  for (int i = ty; i < 64; i += 4) tile[i][tx] = W[(size_t)(r0 + i) * DM + c0 + tx];
  __syncthreads();
  #pragma unroll
  for (int i = ty; i < 64; i += 4) Wt[(size_t)(c0 + i) * DM + r0 + tx] = f2bf(tile[tx][i]);
}

// ---------------- MFMA GEMM: C[M][N] = A[M][K] * Bt[N][K]^T ----------------
// 128(M) x BN(N) tile, 4 waves (2x2), BK=32, global_load_lds width=16 staging.
// MODE 0: float C[m*DM+n]
// MODE 1: bf16 head layout C[((b*NH+h)*S_+s)*HD+d]             (Q, K)
// MODE 2: bf16 V^T layout C[((b*NH+h)*HD+d)*S_+s] via LDS transpose (coalesced)
template <int MODE, int BN>
__device__ __forceinline__ void gemm_body(const ushort* __restrict__ A,
                                          const ushort* __restrict__ Bt,
                                          ushort* __restrict__ Cb,
                                          float* __restrict__ Cf,
                                          ushort* As, ushort* Bs, ushort* Ts) {
  const int K = DM;
  constexpr int CN = BN / 32;                   // n-frags per wave
  int m0 = blockIdx.y * 128;
  int n0 = blockIdx.x * BN;
  int t = threadIdx.x;
  int lane = t & 63, wave = t >> 6;
  int wm = (wave >> 1) * 64, wn = (wave & 1) * (BN / 2);
  int lrow = lane & 15, quad = lane >> 4;

  int Ra = wave * 32;                           // A rows staged by this wave
  int Rb = wave * (BN / 4);                     // B rows staged by this wave
  int srow = lane >> 2, scol = (lane & 3) * 8;  // per-lane 16B chunk within 16-row group

  f32x4 acc[4][CN];
  #pragma unroll
  for (int r = 0; r < 4; ++r)
    #pragma unroll
    for (int c = 0; c < CN; ++c) acc[r][c] = (f32x4){0.f, 0.f, 0.f, 0.f};

  for (int k0 = 0; k0 < K; k0 += 32) {
    const ushort* ga = A + (size_t)(m0 + Ra + srow) * K + k0 + scol;
    const ushort* gb = Bt + (size_t)(n0 + Rb + srow) * K + k0 + scol;
    async16(ga,          As + Ra * 32);
    async16(ga + 16 * K, As + (Ra + 16) * 32);
    async16(gb,          Bs + Rb * 32);
    if (BN == 128) async16(gb + 16 * K, Bs + (Rb + 16) * 32);
    __syncthreads();

    bf16x8 af[4], bfr[CN];
    #pragma unroll
    for (int r = 0; r < 4; ++r)
      af[r] = *(const bf16x8*)(As + (wm + r * 16 + lrow) * 32 + quad * 8);
    #pragma unroll
    for (int c = 0; c < CN; ++c)
      bfr[c] = *(const bf16x8*)(Bs + (wn + c * 16 + lrow) * 32 + quad * 8);
    #pragma unroll
    for (int r = 0; r < 4; ++r)
      #pragma unroll
      for (int c = 0; c < CN; ++c)
        acc[r][c] = __builtin_amdgcn_mfma_f32_16x16x32_bf16(af[r], bfr[c], acc[r][c], 0, 0, 0);
    __syncthreads();
  }

  if constexpr (MODE == 2) {
    // transpose through LDS in two half-passes, then coalesced V^T rows.
    // Ts ALIASES As/Bs (dead after K-loop's trailing barrier).
    int bb = m0 >> 11;            // batch (block never straddles b)
    int s0base = m0 & 2047;
    #pragma unroll
    for (int H = 0; H < 2; ++H) {
      __syncthreads();            // Ts reuse guard (and As/Bs death guard on H=0)
      if ((wave >> 1) == H) {
        #pragma unroll
        for (int r = 0; r < 4; ++r)
          #pragma unroll
          for (int c = 0; c < 4; ++c) {
            uint2 pk;
            pk.x = (unsigned)f2bf(acc[r][c][0]) | ((unsigned)f2bf(acc[r][c][1]) << 16);
            pk.y = (unsigned)f2bf(acc[r][c][2]) | ((unsigned)f2bf(acc[r][c][3]) << 16);
            *(uint2*)(Ts + (wn + c * 16 + lrow) * 72 + r * 16 + quad * 4) = pk;
          }
      }
      __syncthreads();
      #pragma unroll
      for (int i = 0; i < 4; ++i) {
        int id = t + i * 256;
        int nn = id >> 3, col = (id & 7) * 8;
        uint4 v = *(const uint4*)(Ts + nn * 72 + col);
        int h2 = (n0 >> 6) + (nn >> 6), d2 = nn & 63;
        size_t dst = (((size_t)(bb * NH + h2)) * HD + d2) * (size_t)S_ + s0base + H * 64 + col;
        *(uint4*)(Cb + dst) = v;
      }
    }
  } else {
    // epilogue: C/D layout col=lane&15, row=quad*4+e
    #pragma unroll
    for (int r = 0; r < 4; ++r) {
      #pragma unroll
      for (int c = 0; c < CN; ++c) {
        #pragma unroll
        for (int e = 0; e < 4; ++e) {
          int m = m0 + wm + r * 16 + quad * 4 + e;
          int n = n0 + wn + c * 16 + lrow;
          if (MODE == 0) {
            Cf[(size_t)m * DM + n] = acc[r][c][e];
          } else {
            int b = m >> 11, s = m & 2047, h = n >> 6, d = n & 63;
            Cb[(((size_t)(b * NH + h)) * S_ + s) * HD + d] = f2bf(acc[r][c][e]);
          }
        }
      }
    }
  }
}

// single dispatch for Q, K, V (z = 0,1,2); Ts unioned with As/Bs -> 18.4 KB LDS
// __launch_bounds__(256,3): m97's 164-VGPR / 3-blocks-per-CU operating point
__global__ __launch_bounds__(256, 3) void gemm_qkv(const ushort* __restrict__ A,
                                                   const ushort* __restrict__ wt,
                                                   ushort* __restrict__ qkv) {
  __shared__ __align__(16) ushort smem[9216];   // As[0:4096) Bs[4096:8192); Ts aliases [0:9216)
  ushort* As = smem;
  ushort* Bs = smem + 4096;
  ushort* Ts = smem;
  int z = blockIdx.z;
  if (z < 2)
    gemm_body<1, 128>(A, wt + (size_t)z * (DM * DM), qkv + (size_t)z * ((size_t)M_ * DM),
                      nullptr, As, Bs, Ts);
  else
    gemm_body<2, 128>(A, wt + (size_t)2 * (DM * DM), qkv + (size_t)2 * ((size_t)M_ * DM),
                      nullptr, As, Bs, Ts);
}

// 128x64 tiles -> grid 512, 12 KB LDS, 3 blocks/CU target
__global__ __launch_bounds__(256, 3) void gemm_out(const ushort* __restrict__ A,
                                                   const ushort* __restrict__ wt,
                                                   float* __restrict__ C) {
  __shared__ __align__(16) ushort As[128 * 32];
  __shared__ __align__(16) ushort Bs[64 * 32];
  gemm_body<0, 64>(A, wt, nullptr, C, As, Bs, nullptr);
}

// ---------------- MFMA flash attention v6 (round-11 verbatim) ----------------
#define EXPC 0.18033688011f   // 0.125 * log2(e)

struct AttnState {
  f32x4 o[4];
  float l;
};

template <bool MASKED>
__device__ __forceinline__ void attn_tile_compute(
    int q0, int kt, bf16x8 qf0, bf16x8 qf1,
    const bf16x8 kf0[4], const bf16x8 kf1[4],
    const bf16x8 vf0[4], const bf16x8 vf1[4],
    ushort* pl, AttnState& st, int lrow, int quad) {
  f32x4 s[4];
  #pragma unroll
  for (int c = 0; c < 4; ++c) {
    f32x4 z = (f32x4){0.f, 0.f, 0.f, 0.f};
    z = __builtin_amdgcn_mfma_f32_16x16x32_bf16(kf0[c], qf0, z, 0, 0, 0);
    z = __builtin_amdgcn_mfma_f32_16x16x32_bf16(kf1[c], qf1, z, 0, 0, 0);
    s[c] = z;
  }
  int q = q0 + lrow;
  #pragma unroll
  for (int c = 0; c < 4; ++c) {
    float pv[4];
    #pragma unroll
    for (int e = 0; e < 4; ++e) {
      float v = __builtin_amdgcn_exp2f(s[c][e] * EXPC);
      if (MASKED) {
        int key = kt + c * 16 + quad * 4 + e;
        v = (key <= q) ? v : 0.f;
      }
      pv[e] = v;
      st.l += v;
    }
    uint2 pk;
    pk.x = __builtin_amdgcn_perm(fbits(pv[1]), fbits(pv[0]), 0x07060302u);
    pk.y = __builtin_amdgcn_perm(fbits(pv[3]), fbits(pv[2]), 0x07060302u);
    *(uint2*)(pl + lrow * 72 + c * 16 + quad * 4) = pk;
  }
  bf16x8 pf0 = *(const bf16x8*)(pl + lrow * 72 + quad * 8);
  bf16x8 pf1 = *(const bf16x8*)(pl + lrow * 72 + 32 + quad * 8);
  #pragma unroll
  for (int dt = 0; dt < 4; ++dt) {
    st.o[dt] = __builtin_amdgcn_mfma_f32_16x16x32_bf16(pf0, vf0[dt], st.o[dt], 0, 0, 0);
    st.o[dt] = __builtin_amdgcn_mfma_f32_16x16x32_bf16(pf1, vf1[dt], st.o[dt], 0, 0, 0);
  }
}

__global__ __launch_bounds__(256, 2) void attn_mfma(const ushort* __restrict__ Q,
                                                    const ushort* __restrict__ Kmat,
                                                    const ushort* __restrict__ Vt,
                                                    ushort* __restrict__ ctx) {
  __shared__ __align__(16) ushort Ks[2][64 * 72];    // [key][d]
  __shared__ __align__(16) ushort Vs[2][64 * 72];    // [d][key]
  __shared__ __align__(16) ushort plds[8][16 * 72];  // per-wave P: [wave]=hi, [wave+4]=lo
  int t = threadIdx.x;
  int lane = t & 63, wave = t >> 6;
  int lrow = lane & 15, quad = lane >> 4;
  int bh = blockIdx.y;                 // b*NH + h
  int p = blockIdx.x;                  // pair index 0..15
  int qt_lo = p, qt_hi = 31 - p;
  const ushort* Kb = Kmat + (size_t)bh * S_ * HD;
  const ushort* Vb = Vt + (size_t)bh * HD * S_;
  ushort* pl_hi = plds[wave];
  ushort* pl_lo = plds[wave + 4];
  int b = bh >> 4, h = bh & 15;

  int r0 = t >> 3, s0 = (t & 7) * 8;              // chunk t
  int r1 = (t + 256) >> 3, s1 = s0;               // chunk t+256

  int q0_lo = qt_lo * 64 + wave * 16;
  int q0_hi = qt_hi * 64 + wave * 16;
  const ushort* Qlo = Q + ((size_t)bh * S_ + q0_lo) * HD;
  const ushort* Qhi = Q + ((size_t)bh * S_ + q0_hi) * HD;
  bf16x8 qlo0 = *(const bf16x8*)(Qlo + (size_t)lrow * HD + quad * 8);
  bf16x8 qlo1 = *(const bf16x8*)(Qlo + (size_t)lrow * HD + 32 + quad * 8);
  bf16x8 qhi0 = *(const bf16x8*)(Qhi + (size_t)lrow * HD + quad * 8);
  bf16x8 qhi1 = *(const bf16x8*)(Qhi + (size_t)lrow * HD + 32 + quad * 8);

  AttnState lo, hi;
  #pragma unroll
  for (int i = 0; i < 4; ++i) {
    lo.o[i] = (f32x4){0.f, 0.f, 0.f, 0.f}; hi.o[i] = (f32x4){0.f, 0.f, 0.f, 0.f};
  }
  lo.l = 0.f; hi.l = 0.f;

  int kend = qt_hi * 64;
  int lo_end = qt_lo * 64;

  {
    uint4 ka = *(const uint4*)(Kb + (size_t)r0 * HD + s0);
    uint4 kb2 = *(const uint4*)(Kb + (size_t)r1 * HD + s1);
    uint4 va = *(const uint4*)(Vb + (size_t)r0 * S_ + s0);
    uint4 vb2 = *(const uint4*)(Vb + (size_t)r1 * S_ + s1);
    *(uint4*)(Ks[0] + r0 * 72 + s0) = ka;
    *(uint4*)(Ks[0] + r1 * 72 + s1) = kb2;
    *(uint4*)(Vs[0] + r0 * 72 + s0) = va;
    *(uint4*)(Vs[0] + r1 * 72 + s1) = vb2;
  }
  __syncthreads();

  for (int kt = 0; kt <= kend; kt += 64) {
    int cur = (kt >> 6) & 1, nxt = cur ^ 1;
    bool has_next = (kt < kend);

    uint4 ka, kb2, va, vb2;
    if (has_next) {
      int ktn = kt + 64;
      ka  = *(const uint4*)(Kb + (size_t)(ktn + r0) * HD + s0);
      kb2 = *(const uint4*)(Kb + (size_t)(ktn + r1) * HD + s1);
      va  = *(const uint4*)(Vb + (size_t)r0 * S_ + ktn + s0);
      vb2 = *(const uint4*)(Vb + (size_t)r1 * S_ + ktn + s1);
    }

    bf16x8 kf0[4], kf1[4], vf0[4], vf1[4];
    #pragma unroll
    for (int c = 0; c < 4; ++c) {
      const ushort* kr = Ks[cur] + (c * 16 + lrow) * 72;
      kf0[c] = *(const bf16x8*)(kr + quad * 8);
      kf1[c] = *(const bf16x8*)(kr + 32 + quad * 8);
      const ushort* vr = Vs[cur] + (c * 16 + lrow) * 72;
      vf0[c] = *(const bf16x8*)(vr + quad * 8);
      vf1[c] = *(const bf16x8*)(vr + 32 + quad * 8);
    }

    if (kt < kend)
      attn_tile_compute<false>(q0_hi, kt, qhi0, qhi1, kf0, kf1, vf0, vf1, pl_hi, hi, lrow, quad);
    else
      attn_tile_compute<true>(q0_hi, kt, qhi0, qhi1, kf0, kf1, vf0, vf1, pl_hi, hi, lrow, quad);
    if (kt < lo_end)
      attn_tile_compute<false>(q0_lo, kt, qlo0, qlo1, kf0, kf1, vf0, vf1, pl_lo, lo, lrow, quad);
    else if (kt == lo_end)
      attn_tile_compute<true>(q0_lo, kt, qlo0, qlo1, kf0, kf1, vf0, vf1, pl_lo, lo, lrow, quad);

    if (has_next) {
      *(uint4*)(Ks[nxt] + r0 * 72 + s0) = ka;
      *(uint4*)(Ks[nxt] + r1 * 72 + s1) = kb2;
      *(uint4*)(Vs[nxt] + r0 * 72 + s0) = va;
      *(uint4*)(Vs[nxt] + r1 * 72 + s1) = vb2;
    }
    __syncthreads();
  }

  #pragma unroll
  for (int half = 0; half < 2; ++half) {
    AttnState& st = half ? hi : lo;
    int q0 = half ? q0_hi : q0_lo;
    float l = st.l;
    l += __shfl_xor(l, 16);
    l += __shfl_xor(l, 32);
    float rl = 1.0f / l;
    #pragma unroll
    for (int e = 0; e < 4; ++e) {
      float rinv = __shfl(rl, quad * 4 + e);
      int q = q0 + quad * 4 + e;
      #pragma unroll
      for (int dt = 0; dt < 4; ++dt)
        ctx[((size_t)b * S_ + q) * DM + h * HD + dt * 16 + lrow] = f2bf(st.o[dt][e] * rinv);
    }
  }
}

// ---------------- launch ----------------
extern "C" void kernel_launch(void* const* d_in, const int* in_sizes, int n_in,
                              void* d_out, int out_size, void* d_ws, size_t ws_size,
                              hipStream_t stream) {
  const float* x  = (const float*)d_in[0];
  const float* Wq = (const float*)d_in[1];
  const float* Wk = (const float*)d_in[2];
  const float* Wv = (const float*)d_in[3];
  const float* Wo = (const float*)d_in[4];
  float* out = (float*)d_out;
  ushort* ws = (ushort*)d_ws;

  ushort* xb  = ws;                                   // 4M elem bf16 x
  ushort* wt  = xb + (size_t)M_ * DM;                 // 4 x 1M elem (Wq^T,Wk^T,Wv^T,Wo^T) bf16
  ushort* qkv = wt + (size_t)4 * DM * DM;             // Q,K [b,h,s,d]; V^T [b,h,d,s] bf16
  ushort* ctx = qkv + (size_t)3 * M_ * DM;            // 4M elem [B,S,DM] bf16

  cvt_prep<<<dim3(16, 16, 5), dim3(64, 4), 0, stream>>>(x, Wq, Wk, Wv, Wo, wt, xb);
  gemm_qkv<<<dim3(DM / 128, M_ / 128, 3), 256, 0, stream>>>(xb, wt, qkv);
  attn_mfma<<<dim3(16, B_ * NH), 256, 0, stream>>>(qkv, qkv + (size_t)M_ * DM,
                                                   qkv + (size_t)2 * M_ * DM, ctx);
  gemm_out<<<dim3(DM / 64, M_ / 128), 256, 0, stream>>>(ctx, wt + (size_t)3 * DM * DM, out);
}